// Round 3
// baseline (101061.096 us; speedup 1.0000x reference)
//
#include <hip/hip_runtime.h>
#include <math.h>
#include <stdint.h>

// MGU RNN, T=8192, IN=128, H=1024, L=3 — R9: epoch-gated h-handoff.
//
// R8 post-mortem: halving rec-layer dot work changed nothing -> the step is
// latency/contention-bound on the h all-to-all, not VALU-bound. R8's fabric
// has every thread re-polling 4 tagged MALL words continuously (~8 KB/WG per
// ~900cy round, ~10 TB/s aggregate tag traffic) and each consumer waits on
// the slowest of 128 producer WGs.
//
// R9 keeps R8's structure (grid, army offload, rings, backpressure, parity
// h rows, 256-reg-safe launch bounds) and changes ONLY the h-handoff:
//   producer: lanes q<2 drop hy into LDS; barrier2; tid0 stores the WG's 8
//     contiguous h words (64 B), s_waitcnt vmcnt(0), then bumps epoch[r].
//   consumer: speculatively issues its 4 data loads AND the epoch check
//     overlapped; if epochs not ready, spins on 128 packed ints
//     (0.5 KB/round, 16x less traffic); per-word tag-poll remains as a pure
//     safety fallback (ordering violation => spin/fallback, never stale
//     data; 0xAA poison is negative under signed compare => no init needed).
// Off-critical-path spin loops (armies, gi, backpressure) get s_sleep
// backoff to cut their MALL contention contribution.

#define T_STEPS 8192
#define HDIM 1024
#define RING 128
#define SLACK (RING - 16)

typedef unsigned long long u64;

__device__ __forceinline__ u64 agload64(const u64* p) {
    return __hip_atomic_load(p, __ATOMIC_RELAXED, __HIP_MEMORY_SCOPE_AGENT);
}
__device__ __forceinline__ void agstore64(u64* p, u64 v) {
    __hip_atomic_store(p, v, __ATOMIC_RELAXED, __HIP_MEMORY_SCOPE_AGENT);
}
__device__ __forceinline__ int agloadi(const int* p) {
    return __hip_atomic_load(p, __ATOMIC_RELAXED, __HIP_MEMORY_SCOPE_AGENT);
}
__device__ __forceinline__ void agstorei(int* p, int v) {
    __hip_atomic_store(p, v, __ATOMIC_RELAXED, __HIP_MEMORY_SCOPE_AGENT);
}
__device__ __forceinline__ float dot4(float4 a, float4 b) {
    return a.x * b.x + a.y * b.y + a.z * b.z + a.w * b.w;
}
__device__ __forceinline__ u64 pack(float v, int tag) {
    return ((u64)(unsigned)tag << 32) | (u64)__float_as_uint(v);
}
__device__ __forceinline__ void opaque4(float4& v) {
    asm volatile("" : "+v"(v.x), "+v"(v.y), "+v"(v.z), "+v"(v.w));
}
__device__ __forceinline__ void opaque2(float2& v) {
    asm volatile("" : "+v"(v.x), "+v"(v.y));
}

// MIN over a 64-int per-WG progress array (monotone snapshots -> stale MIN
// is conservative/safe).
__device__ __forceinline__ int minscan64(const int* parr, int q) {
    int p = agloadi(parr + q);
#pragma unroll
    for (int off = 32; off; off >>= 1) {
        const int o = __shfl_xor(p, off, 64);
        p = p < o ? p : o;
    }
    return p;
}

// ================= recurrence layer =================
// 128 WGs x 256 threads. WG r owns units [8r, 8r+8); wave a owns 2 units
// jb = 8r + 2a, jb+1. Per-thread hh weights: 64 floats (16 float4).
template <int L>
__device__ void rec_layer(float* __restrict__ s_h,        // LDS [2][1024]
                          float* __restrict__ s_x0,       // LDS [2][128] (L0)
                          float (*__restrict__ s_gi)[16], // LDS [2][16]  (L>0)
                          float* __restrict__ s_pub,      // LDS [8]
                          const float* __restrict__ S,
                          const float* __restrict__ h0,
                          const float* __restrict__ w_ih,
                          const float* __restrict__ b_ih,
                          const float* __restrict__ w_hh,
                          const float* __restrict__ b_hh,
                          const u64* __restrict__ giRing,  // L>0
                          u64* __restrict__ ring_out,      // L<2
                          float* __restrict__ xout,        // L==2
                          u64* __restrict__ htag,          // [2][1024]
                          int* __restrict__ ep,            // layer epochs[128]
                          const int* __restrict__ progArr, // L<2: 64 words
                          int* __restrict__ progGiSelf,    // L>0: 1 word
                          int r)
{
    const int tid = threadIdx.x;       // 0..255
    const int a   = tid >> 6;          // wave 0..3
    const int q   = tid & 63;
    const int jb  = r * 8 + 2 * a;

    // ---- hh weights -> VGPRs (64 floats/thread), pinned opaque ----
    float4 wf[2][4], wn[2][4];
#pragma unroll
    for (int g = 0; g < 2; ++g) {
        const float* rf = w_hh + (size_t)(jb + g) * HDIM;
        const float* rn = w_hh + (size_t)(HDIM + jb + g) * HDIM;
#pragma unroll
        for (int m = 0; m < 4; ++m) {
            wf[g][m] = *(const float4*)(rf + 4 * q + 256 * m);
            wn[g][m] = *(const float4*)(rn + 4 * q + 256 * m);
            opaque4(wf[g][m]); opaque4(wn[g][m]);
        }
    }
    float2 wif2[2] = {}, win2[2] = {};
    float bFv[2], bInv[2] = {0.f, 0.f}, bHnv[2];
    if constexpr (L == 0) {
#pragma unroll
        for (int g = 0; g < 2; ++g) {
            wif2[g] = *(const float2*)(w_ih + (size_t)(jb + g) * 128 + 2 * q);
            win2[g] = *(const float2*)(w_ih + (size_t)(HDIM + jb + g) * 128 + 2 * q);
            opaque2(wif2[g]); opaque2(win2[g]);
            bFv[g]  = b_ih[jb + g] + b_hh[jb + g];
            bInv[g] = b_ih[HDIM + jb + g];
            bHnv[g] = b_hh[HDIM + jb + g];
        }
    } else {
#pragma unroll
        for (int g = 0; g < 2; ++g) {
            bFv[g]  = b_hh[jb + g];          // hh forget bias
            bHnv[g] = b_hh[HDIM + jb + g];   // hh new bias
        }
    }

    int lastProg = 0;

    for (int t = 0; t < T_STEPS; ++t) {
        const int par = t & 1;
        float* hD = s_h + par * HDIM;
        const u64* hrow = htag + (size_t)((t + 1) & 1) * HDIM;  // h_{t-1}
        u64*       hpub = htag + (size_t)par * HDIM;

        // ---- ring backpressure vs army per-WG progress MIN (L<2) ----
        if constexpr (L < 2) {
            if (t - lastProg > SLACK) {
                do {
                    __builtin_amdgcn_s_sleep(8);
                    lastProg = minscan64(progArr, q);
                } while (t - lastProg > SLACK);
            }
        }

        // ---- input acquire ----
        if constexpr (L == 0) {
            float* xD = s_x0 + par * 128;
            if (tid < 32)
                ((float4*)xD)[tid] = ((const float4*)(S + (size_t)t * 128))[tid];
        } else {
            // 16 gi words/WG (8 f + 8 n); ready in steady state (army ahead)
            if (tid < 16) {
                const unsigned xe = (unsigned)(t + 1);
                const u64* p = giRing + (size_t)(t & (RING - 1)) * 2048
                             + (tid < 8 ? (size_t)(8 * r + tid)
                                        : (size_t)(1024 + 8 * r + (tid - 8)));
                u64 w = agload64(p);
                while ((unsigned)(w >> 32) != xe) {
                    __builtin_amdgcn_s_sleep(2);
                    w = agload64(p);
                }
                s_gi[par][tid] = __uint_as_float((unsigned)w);
            }
        }

        // ---- h acquire: overlapped speculative data + epoch gate ----
        if (t == 0) {
            hD[tid]       = h0[tid];
            hD[tid + 256] = h0[tid + 256];
            hD[tid + 512] = h0[tid + 512];
            hD[tid + 768] = h0[tid + 768];
        } else {
            const unsigned he = (unsigned)t;
            // speculative data loads + epoch loads, all in flight together
            u64 w0 = agload64(hrow + tid);
            u64 w1 = agload64(hrow + tid + 256);
            u64 w2 = agload64(hrow + tid + 512);
            u64 w3 = agload64(hrow + tid + 768);
            int e0 = agloadi(ep + q);
            int e1 = agloadi(ep + q + 64);
            // epoch gate: all 128 producer WGs must have finished step t-1.
            // (0xAA poison is negative -> signed compare safe, no init.)
            while (!__all(e0 >= t && e1 >= t)) {
                e0 = agloadi(ep + q);
                e1 = agloadi(ep + q + 64);
            }
            // tags now guaranteed by producer ordering; loops below are the
            // safety fallback and exit on the already-loaded value normally.
            while ((unsigned)(w0 >> 32) != he) w0 = agload64(hrow + tid);
            while ((unsigned)(w1 >> 32) != he) w1 = agload64(hrow + tid + 256);
            while ((unsigned)(w2 >> 32) != he) w2 = agload64(hrow + tid + 512);
            while ((unsigned)(w3 >> 32) != he) w3 = agload64(hrow + tid + 768);
            hD[tid]       = __uint_as_float((unsigned)w0);
            hD[tid + 256] = __uint_as_float((unsigned)w1);
            hD[tid + 512] = __uint_as_float((unsigned)w2);
            hD[tid + 768] = __uint_as_float((unsigned)w3);
        }
        __syncthreads();   // barrier 1: h (and gi/x) staged for this step

        // gi consumption progress: r0's barrier + h-coupling bounds all WGs
        if constexpr (L > 0) {
            if (r == 0 && tid == 0) agstorei(progGiSelf, t + 1);
        }

        // ---- hh dots (16 dot4/thread; L0 adds its K=128 x-part) ----
        float aF[2]  = {0.f, 0.f};
        float aNh[2] = {0.f, 0.f};
        float aNi[2] = {0.f, 0.f};
#pragma unroll
        for (int m = 0; m < 4; ++m) {
            const float4 h4 = ((const float4*)hD)[q + 64 * m];
#pragma unroll
            for (int g = 0; g < 2; ++g) {
                aF[g]  += dot4(wf[g][m], h4);
                aNh[g] += dot4(wn[g][m], h4);
            }
        }
        if constexpr (L == 0) {
            const float* xD = s_x0 + par * 128;
            const float2 x2 = *(const float2*)&xD[2 * q];
#pragma unroll
            for (int g = 0; g < 2; ++g) {
                aF[g]  += wif2[g].x * x2.x + wif2[g].y * x2.y;
                aNi[g] += win2[g].x * x2.x + win2[g].y * x2.y;
            }
        }

        // ---- two-phase reduction (2 units/wave) ----
#pragma unroll
        for (int g = 0; g < 2; ++g) {
            aF[g]  += __shfl_xor(aF[g],  1, 64);
            aNh[g] += __shfl_xor(aNh[g], 1, 64);
            if constexpr (L == 0) aNi[g] += __shfl_xor(aNi[g], 1, 64);
        }
        const int gsl = q & 1;
        float vF  = gsl ? aF[1]  : aF[0];
        float vNh = gsl ? aNh[1] : aNh[0];
        float vNi = 0.f;
        if constexpr (L == 0) vNi = gsl ? aNi[1] : aNi[0];
#pragma unroll
        for (int off = 2; off <= 32; off <<= 1) {
            vF  += __shfl_xor(vF,  off, 64);
            vNh += __shfl_xor(vNh, off, 64);
            if constexpr (L == 0) vNi += __shfl_xor(vNi, off, 64);
        }

        // ---- gate: lane 0 -> unit jb, lane 1 -> unit jb+1 ----
        if (q < 2) {
            const int   j  = jb + q;
            const float hp = hD[j];
            float f, n;
            if constexpr (L == 0) {
                const float cF  = gsl ? bFv[1]  : bFv[0];
                const float cIn = gsl ? bInv[1] : bInv[0];
                const float cHn = gsl ? bHnv[1] : bHnv[0];
                f = 1.f / (1.f + expf(-(vF + cF)));
                n = tanhf(vNi + cIn + f * (vNh + cHn));
            } else {
                const float cHf = gsl ? bFv[1]  : bFv[0];
                const float cHn = gsl ? bHnv[1] : bHnv[0];
                const float gf  = s_gi[par][2 * a + q];       // ih f + b_ih
                const float gn  = s_gi[par][8 + 2 * a + q];   // ih n + b_ih
                f = 1.f / (1.f + expf(-(gf + vF + cHf)));
                n = tanhf(gn + f * (vNh + cHn));
            }
            const float hy = n + (1.f - f) * (hp - n);
            s_pub[2 * a + q] = hy;                       // -> tid0 publisher
            if constexpr (L < 2) {
                agstore64(ring_out + (size_t)(t & (RING - 1)) * HDIM + j,
                          pack(hy, t + 1));
            } else {
                xout[(size_t)t * HDIM + j] = hy;
            }
        }
        __syncthreads();   // barrier 2: s_pub complete

        // ---- single-thread ordered publish: 8 h words, drain, epoch ----
        if (tid == 0) {
            u64* dst = hpub + (size_t)(r * 8);
#pragma unroll
            for (int u = 0; u < 8; ++u)
                agstore64(dst + u, pack(s_pub[u], t + 1));
            asm volatile("s_waitcnt vmcnt(0)" ::: "memory");
            agstorei(ep + r, t + 1);
        }
        // parity LDS buffers + two barriers bound intra-WG skew to 1 step.
    }
}

// ================= army (input-projection GEMV) =================
// 64 WGs x 256 threads per layer. WG r owns units [16r, 16r+16); wave a
// owns 4 units jb..jb+3 (jb = 16r + 4a). 128 weight floats/thread.
__device__ void army_layer(float* __restrict__ s_x,        // LDS [2][1024]
                           const u64* __restrict__ xring,
                           u64* __restrict__ giRing,
                           const float* __restrict__ w_ih,
                           const float* __restrict__ b_ih,
                           const int* __restrict__ progGiNext, // 1 word
                           int* __restrict__ progSelf,         // own word
                           int r)
{
    const int tid = threadIdx.x;
    const int a   = tid >> 6;
    const int q   = tid & 63;
    const int jb  = r * 16 + 4 * a;

    float4 wiF[4][4], wiN[4][4];
#pragma unroll
    for (int g = 0; g < 4; ++g) {
        const float* rf = w_ih + (size_t)(jb + g) * HDIM;
        const float* rn = w_ih + (size_t)(HDIM + jb + g) * HDIM;
#pragma unroll
        for (int m = 0; m < 4; ++m) {
            wiF[g][m] = *(const float4*)(rf + 4 * q + 256 * m);
            wiN[g][m] = *(const float4*)(rn + 4 * q + 256 * m);
            opaque4(wiF[g][m]); opaque4(wiN[g][m]);
        }
    }
    float bIF[4], bIN[4];
#pragma unroll
    for (int g = 0; g < 4; ++g) {
        bIF[g] = b_ih[jb + g];
        bIN[g] = b_ih[HDIM + jb + g];
    }

    int lastProg = 0;

    for (int t = 0; t < T_STEPS; ++t) {
        const int par = t & 1;
        float* xD = s_x + par * HDIM;

        // gi-ring backpressure on the consumer layer's progress
        if (t - lastProg > SLACK) {
            do {
                __builtin_amdgcn_s_sleep(8);
                lastProg = agloadi(progGiNext);
            } while (t - lastProg > SLACK);
        }

        // x acquire: 4 tagged words/thread, s_sleep backoff on miss
        // (armies trail the producer by design; naps cost them nothing
        //  serially and cut their MALL poll-traffic contribution)
        {
            const unsigned xe = (unsigned)(t + 1);
            const u64* xrow = xring + (size_t)(t & (RING - 1)) * HDIM;
            u64 w0 = 0, w1 = 0, w2 = 0, w3 = 0;
            bool d0 = false, d1 = false, d2 = false, d3 = false;
            for (;;) {
                if (!d0) { w0 = agload64(xrow + tid);       d0 = ((unsigned)(w0 >> 32) == xe); }
                if (!d1) { w1 = agload64(xrow + tid + 256); d1 = ((unsigned)(w1 >> 32) == xe); }
                if (!d2) { w2 = agload64(xrow + tid + 512); d2 = ((unsigned)(w2 >> 32) == xe); }
                if (!d3) { w3 = agload64(xrow + tid + 768); d3 = ((unsigned)(w3 >> 32) == xe); }
                if (d0 && d1 && d2 && d3) break;
                __builtin_amdgcn_s_sleep(2);
            }
            xD[tid]       = __uint_as_float((unsigned)w0);
            xD[tid + 256] = __uint_as_float((unsigned)w1);
            xD[tid + 512] = __uint_as_float((unsigned)w2);
            xD[tid + 768] = __uint_as_float((unsigned)w3);
        }
        __syncthreads();

        // per-WG consumption progress (army WGs are not step-coupled)
        if (tid == 0) agstorei(progSelf, t + 1);

        // dots: 4 units x 2 rows x 4 chunks = 32 dot4/thread
        float aGF[4] = {0.f, 0.f, 0.f, 0.f};
        float aGN[4] = {0.f, 0.f, 0.f, 0.f};
#pragma unroll
        for (int m = 0; m < 4; ++m) {
            const float4 x4 = ((const float4*)xD)[q + 64 * m];
#pragma unroll
            for (int g = 0; g < 4; ++g) {
                aGF[g] += dot4(wiF[g][m], x4);
                aGN[g] += dot4(wiN[g][m], x4);
            }
        }

        // three-phase reduction for 4 units
#pragma unroll
        for (int g = 0; g < 4; ++g) {
            aGF[g] += __shfl_xor(aGF[g], 1, 64);
            aGN[g] += __shfl_xor(aGN[g], 1, 64);
        }
        const int s1 = q & 1;
        float bF0 = s1 ? aGF[1] : aGF[0];
        float bF1 = s1 ? aGF[3] : aGF[2];
        float bN0 = s1 ? aGN[1] : aGN[0];
        float bN1 = s1 ? aGN[3] : aGN[2];
        bF0 += __shfl_xor(bF0, 2, 64);
        bF1 += __shfl_xor(bF1, 2, 64);
        bN0 += __shfl_xor(bN0, 2, 64);
        bN1 += __shfl_xor(bN1, 2, 64);
        const int s2 = (q >> 1) & 1;
        float vGF = s2 ? bF1 : bF0;
        float vGN = s2 ? bN1 : bN0;
#pragma unroll
        for (int off = 4; off <= 32; off <<= 1) {
            vGF += __shfl_xor(vGF, off, 64);
            vGN += __shfl_xor(vGN, off, 64);
        }

        // publish: lane q<4 -> unit jb+q (static-index bias select)
        if (q < 4) {
            const int j = jb + q;
            u64* grow = giRing + (size_t)(t & (RING - 1)) * 2048;
            const float bf = s1 ? (s2 ? bIF[3] : bIF[1]) : (s2 ? bIF[2] : bIF[0]);
            const float bn = s1 ? (s2 ? bIN[3] : bIN[1]) : (s2 ? bIN[2] : bIN[0]);
            agstore64(grow + j,        pack(vGF + bf, t + 1));
            agstore64(grow + 1024 + j, pack(vGN + bn, t + 1));
        }
    }
}

// ================= kernels =================
__global__ __launch_bounds__(256, 2)   // 256-reg cap, 2 blocks/CU GUARANTEED
void mgu_pipe(const float* __restrict__ S,
              const float* __restrict__ h0,
              const float* __restrict__ w_ih0, const float* __restrict__ b_ih0,
              const float* __restrict__ w_hh0, const float* __restrict__ b_hh0,
              const float* __restrict__ w_ih_r, const float* __restrict__ b_ih_r,
              const float* __restrict__ w_hh_r, const float* __restrict__ b_hh_r,
              float* __restrict__ xbuf2, u64* __restrict__ ring0,
              u64* __restrict__ ring1, u64* __restrict__ gi1,
              u64* __restrict__ gi2, u64* __restrict__ htag,
              int* __restrict__ prog, int* __restrict__ epochs)
{
    __shared__ __align__(16) float s_h[2 * HDIM];   // rec: h / army: x
    __shared__ __align__(16) float s_x0[2 * 128];   // L0 S-row staging
    __shared__ float s_gi[2][16];                   // rec L>0 gi staging
    __shared__ float s_pub[8];                      // rec publish funnel

    int* prog_gi1 = prog + 0;     // L1 gi consumption (single)
    int* prog_gi2 = prog + 16;    // L2 gi consumption (single)
    int* prog_a3  = prog + 64;    // army3 per-WG x consumption [64]
    int* prog_a4  = prog + 128;   // army4 per-WG x consumption [64]

    const int bid = blockIdx.x;
    if (bid < 128) {
        rec_layer<0>(s_h, s_x0, s_gi, s_pub, S, h0,
                     w_ih0, b_ih0, w_hh0, b_hh0,
                     nullptr, ring0, nullptr,
                     htag, epochs, prog_a3, nullptr, bid);
    } else if (bid < 256) {
        rec_layer<1>(s_h, nullptr, s_gi, s_pub, nullptr, h0 + HDIM,
                     nullptr, nullptr, w_hh_r, b_hh_r,
                     gi1, ring1, nullptr,
                     htag + 2 * HDIM, epochs + 128, prog_a4, prog_gi1,
                     bid - 128);
    } else if (bid < 384) {
        rec_layer<2>(s_h, nullptr, s_gi, s_pub, nullptr, h0 + 2 * HDIM,
                     nullptr, nullptr, w_hh_r + 2048 * 1024, b_hh_r + 2048,
                     gi2, nullptr, xbuf2,
                     htag + 4 * HDIM, epochs + 256, nullptr, prog_gi2,
                     bid - 256);
    } else if (bid < 448) {
        army_layer(s_h, ring0, gi1, w_ih_r, b_ih_r,
                   prog_gi1, prog_a3 + (bid - 384), bid - 384);
    } else {
        army_layer(s_h, ring1, gi2, w_ih_r + 2048 * 1024, b_ih_r + 2048,
                   prog_gi2, prog_a4 + (bid - 448), bid - 448);
    }
}

__global__ __launch_bounds__(256)
void mgu_out(const float* __restrict__ x,       // [T, H]
             const float* __restrict__ w_out,   // [1, H]
             const float* __restrict__ b_out,   // [1]
             float* __restrict__ out)           // [T]
{
    const int wave = threadIdx.x >> 6;
    const int lane = threadIdx.x & 63;
    const int t = blockIdx.x * 4 + wave;
    float acc = 0.f;
#pragma unroll
    for (int m = 0; m < 4; ++m) {
        const int i4 = lane + 64 * m;
        const float4 x4 = ((const float4*)(x + (size_t)t * HDIM))[i4];
        const float4 w4 = ((const float4*)w_out)[i4];
        acc += dot4(x4, w4);
    }
#pragma unroll
    for (int off = 32; off > 0; off >>= 1) acc += __shfl_xor(acc, off, 64);
    if (lane == 0) out[t] = acc + b_out[0];
}

extern "C" void kernel_launch(void* const* d_in, const int* in_sizes, int n_in,
                              void* d_out, int out_size, void* d_ws, size_t ws_size,
                              hipStream_t stream) {
    const float* S      = (const float*)d_in[0];   // [8192,128]
    const float* h0     = (const float*)d_in[1];   // [3,1024]
    const float* w_ih0  = (const float*)d_in[2];   // [2048,128]
    const float* w_hh0  = (const float*)d_in[3];   // [2048,1024]
    const float* b_ih0  = (const float*)d_in[4];   // [2048]
    const float* b_hh0  = (const float*)d_in[5];   // [2048]
    const float* w_ih_r = (const float*)d_in[6];   // [2,2048,1024]
    const float* w_hh_r = (const float*)d_in[7];   // [2,2048,1024]
    const float* b_ih_r = (const float*)d_in[8];   // [2,2048]
    const float* b_hh_r = (const float*)d_in[9];   // [2,2048]
    const float* w_out  = (const float*)d_in[10];  // [1,1024]
    const float* b_out  = (const float*)d_in[11];  // [1]
    float* out = (float*)d_out;                    // [8192]

    char* ws = (char*)d_ws;
    float* xbuf2 = (float*)(ws);                        // 32 MB [T,H] f32
    u64*   ring0 = (u64*)(ws + (32u << 20));            // 1 MB  [RING,H] u64
    u64*   ring1 = (u64*)(ws + (33u << 20));            // 1 MB
    u64*   gi1   = (u64*)(ws + (34u << 20));            // 2 MB  [RING,2H] u64
    u64*   gi2   = (u64*)(ws + (36u << 20));            // 2 MB
    u64*   htag  = (u64*)(ws + (38u << 20));            // 3 x [2,H] u64 = 48KB
    int*   prog  = (int*)(ws + (38u << 20) + (64u << 10));   // 192 ints
    int*   epochs= (int*)(ws + (38u << 20) + (80u << 10));   // 3 x 128 ints

    // No init kernel: tags use exact-match vs 0xAA poison; epochs/progress
    // use signed compares (0xAAAAAAAA is negative).
    mgu_pipe<<<512, 256, 0, stream>>>(S, h0, w_ih0, b_ih0, w_hh0, b_hh0,
                                      w_ih_r, b_ih_r, w_hh_r, b_hh_r,
                                      xbuf2, ring0, ring1, gi1, gi2,
                                      htag, prog, epochs);
    mgu_out<<<2048, 256, 0, stream>>>(xbuf2, w_out, b_out, out);
}

// Round 4
// 38504.892 us; speedup vs baseline: 2.6246x; 2.6246x over previous
//
#include <hip/hip_runtime.h>
#include <math.h>
#include <stdint.h>

// MGU RNN, T=8192, IN=128, H=1024, L=3 — R10: XCD-local h-exchange, R6 regs.
//
// Evidence so far: R8 (half the rec VALU work) == R6 -> step time is the
// MALL round-trip of the h all-to-all. R9 (concentrated epoch polling) was
// 4x WORSE -> polling must stay DISTRIBUTED (one tagged word per thread).
// R7 (XCD-local attempt) died of register caps (launch_bounds(512,4) ->
// 128-reg cap -> per-step spills), not of the scope mechanism.
//
// R10 isolates the XCD-local mechanism with R6's proven register regime:
//   - rec layer l = 32 WGs x 512 thr = 32 CUs = ONE XCD (role l = bid&7,
//     round-robin block->XCD). 32 units/WG, 4/wave; hh weights 128 f/thread.
//   - __launch_bounds__(512,2): 256-reg cap, 1 block/CU (R6-proven, no spill)
//   - h publish: dual-store sc0 (home L2) + sc1 (MALL); h poll: sc0 rounds
//     (~300cy) with sticky per-thread agent-scope fallback (fed by the sc1
//     copy) -> misplacement/semantics failure degrades to ~R6, never wrong
//     (tag+data share one atomic 64b word; tags strictly increasing).
//   - armies (XCDs 3/4) compute gi = w_ih·x + b_ih for layers 1/2 off the
//     critical path via the R8 agent-scope ring fabric (proven).
//   - rec gi/S loads issued BEFORE the h poll -> MALL RT hidden under it.
// All R6/R8 overwrite-safety arguments carry over: parity-2 h rows, 128-row
// rings, amortized backpressure (minscan over per-WG army progress), and
// h-coupling (a WG entering step t proves every same-layer WG finished t-1).

#define T_STEPS 8192
#define HDIM 1024
#define RING 128
#define SLACK (RING - 16)
#define HSPIN_FB 3000

typedef unsigned long long u64;

__device__ __forceinline__ u64 agload64(const u64* p) {
    return __hip_atomic_load(p, __ATOMIC_RELAXED, __HIP_MEMORY_SCOPE_AGENT);
}
__device__ __forceinline__ void agstore64(u64* p, u64 v) {
    __hip_atomic_store(p, v, __ATOMIC_RELAXED, __HIP_MEMORY_SCOPE_AGENT);
}
__device__ __forceinline__ int agloadi(const int* p) {
    return __hip_atomic_load(p, __ATOMIC_RELAXED, __HIP_MEMORY_SCOPE_AGENT);
}
__device__ __forceinline__ void agstorei(int* p, int v) {
    __hip_atomic_store(p, v, __ATOMIC_RELAXED, __HIP_MEMORY_SCOPE_AGENT);
}
__device__ __forceinline__ float dot4(float4 a, float4 b) {
    return a.x * b.x + a.y * b.y + a.z * b.z + a.w * b.w;
}
__device__ __forceinline__ u64 pack(float v, int tag) {
    return ((u64)(unsigned)tag << 32) | (u64)__float_as_uint(v);
}
__device__ __forceinline__ void opaque4(float4& v) {
    asm volatile("" : "+v"(v.x), "+v"(v.y), "+v"(v.z), "+v"(v.w));
}
__device__ __forceinline__ void opaque2(float2& v) {
    asm volatile("" : "+v"(v.x), "+v"(v.y));
}

// sc0 load pair: bypass L1, served by the XCD-local L2 (fast h path).
__device__ __forceinline__ void poll2_sc0(u64& w0, u64& w1,
                                          const u64* p0, const u64* p1) {
    asm volatile("global_load_dwordx2 %0, %2, off sc0\n\t"
                 "global_load_dwordx2 %1, %3, off sc0\n\t"
                 "s_waitcnt vmcnt(0)"
                 : "=&v"(w0), "=&v"(w1)
                 : "v"(p0), "v"(p1)
                 : "memory");
    __builtin_amdgcn_sched_barrier(0);
}
// dual-scope publish: sc0 -> home L2 (fast consumers), sc1 -> MALL
// (sticky-fallback consumers). Identical value twice -> any order is fine.
__device__ __forceinline__ void pub_dual(u64* p, u64 v) {
    asm volatile("global_store_dwordx2 %0, %1, off sc0\n\t"
                 "global_store_dwordx2 %0, %1, off sc1"
                 :: "v"(p), "v"(v) : "memory");
}

// MIN over a 32-int per-WG progress array (monotone snapshots -> stale MIN
// is conservative/safe). Lanes duplicate reads; min over 64 lanes.
__device__ __forceinline__ int minscan32(const int* parr, int q) {
    int p = agloadi(parr + (q & 31));
#pragma unroll
    for (int off = 32; off; off >>= 1) {
        const int o = __shfl_xor(p, off, 64);
        p = p < o ? p : o;
    }
    return p;
}

// ================= recurrence layer =================
// 32 WGs x 512 threads on ONE XCD. WG r owns units [32r, 32r+32); wave a
// owns units jb..jb+3 (jb = 32r + 4a). hh weights: 128 floats/thread.
template <int L>
__device__ void rec_layer(float* __restrict__ s_h,        // LDS [2][1024]
                          float* __restrict__ s_x0,       // LDS [2][128] (L0)
                          float (*__restrict__ s_gi)[64], // LDS [2][64]  (L>0)
                          const float* __restrict__ S,
                          const float* __restrict__ h0,
                          const float* __restrict__ w_ih,
                          const float* __restrict__ b_ih,
                          const float* __restrict__ w_hh,
                          const float* __restrict__ b_hh,
                          const u64* __restrict__ giRing,  // L>0
                          u64* __restrict__ ring_out,      // L<2
                          float* __restrict__ xout,        // L==2
                          u64* __restrict__ htag,          // [2][1024]
                          const int* __restrict__ progArr, // L<2: 32 words
                          int* __restrict__ progGiSelf,    // L>0: 1 word
                          int r)
{
    const int tid = threadIdx.x;       // 0..511
    const int a   = tid >> 6;          // wave 0..7
    const int q   = tid & 63;
    const int jb  = r * 32 + 4 * a;

    // ---- hh weights -> VGPRs (128 floats/thread), pinned opaque ----
    float4 wf[4][4], wn[4][4];
#pragma unroll
    for (int g = 0; g < 4; ++g) {
        const float* rf = w_hh + (size_t)(jb + g) * HDIM;
        const float* rn = w_hh + (size_t)(HDIM + jb + g) * HDIM;
#pragma unroll
        for (int m = 0; m < 4; ++m) {
            wf[g][m] = *(const float4*)(rf + 4 * q + 256 * m);
            wn[g][m] = *(const float4*)(rn + 4 * q + 256 * m);
            opaque4(wf[g][m]); opaque4(wn[g][m]);
        }
    }
    float2 wif2[4] = {}, win2[4] = {};
    float bFv[4], bInv[4] = {}, bHnv[4];
#pragma unroll
    for (int g = 0; g < 4; ++g) {
        if constexpr (L == 0) {
            wif2[g] = *(const float2*)(w_ih + (size_t)(jb + g) * 128 + 2 * q);
            win2[g] = *(const float2*)(w_ih + (size_t)(HDIM + jb + g) * 128 + 2 * q);
            opaque2(wif2[g]); opaque2(win2[g]);
            bFv[g]  = b_ih[jb + g] + b_hh[jb + g];
            bInv[g] = b_ih[HDIM + jb + g];
            bHnv[g] = b_hh[HDIM + jb + g];
        } else {
            bFv[g]  = b_hh[jb + g];          // hh forget bias
            bHnv[g] = b_hh[HDIM + jb + g];   // hh new bias
        }
    }

    int  lastProg = 0;
    bool hslow    = false;   // sticky: sc0 fast path failed -> agent polls

    for (int t = 0; t < T_STEPS; ++t) {
        const int par = t & 1;
        float* hD = s_h + par * HDIM;
        const u64* hrow = htag + (size_t)((t + 1) & 1) * HDIM;  // h_{t-1}
        u64*       hpub = htag + (size_t)par * HDIM;

        // ---- ring backpressure vs army per-WG progress MIN (L<2) ----
        if constexpr (L < 2) {
            if (t - lastProg > SLACK) {
                do { lastProg = minscan32(progArr, q); }
                while (t - lastProg > SLACK);
            }
        }

        // ---- issue inputs EARLY (latency hides under the h poll) ----
        float4 sv;                      // L0 S-row chunk
        u64 gw = 0; const u64* gp = nullptr;   // L>0 gi word
        if constexpr (L == 0) {
            if (tid < 32)
                sv = ((const float4*)(S + (size_t)t * 128))[tid];
        } else {
            // 64 gi words/WG: tid<32 -> f part, 32<=tid<64 -> n part
            if (tid < 64) {
                gp = giRing + (size_t)(t & (RING - 1)) * 2048
                   + (tid < 32 ? (size_t)(32 * r + tid)
                               : (size_t)(1024 + 32 * r + (tid - 32)));
                gw = agload64(gp);      // in flight during h poll
            }
        }

        // ---- h acquire: 2 words/thread, sc0 fast / sticky agent slow ----
        if (t == 0) {
            hD[tid]       = h0[tid];
            hD[tid + 512] = h0[tid + 512];
        } else {
            const unsigned he = (unsigned)t;
            const u64* p0 = hrow + tid;
            const u64* p1 = hrow + tid + 512;
            u64 hw0 = 0, hw1 = 0;
            bool done = false;
            if (!hslow) {
                int spins = 0;
                for (;;) {
                    poll2_sc0(hw0, hw1, p0, p1);
                    if ((unsigned)(hw0 >> 32) == he &&
                        (unsigned)(hw1 >> 32) == he) { done = true; break; }
                    if (++spins > HSPIN_FB) { hslow = true; break; }
                }
            }
            if (!done) {   // agent-scope distributed poll (sc1 copy feeds it)
                bool d0 = ((unsigned)(hw0 >> 32) == he);
                bool d1 = ((unsigned)(hw1 >> 32) == he);
                while (!(d0 && d1)) {
                    if (!d0) { hw0 = agload64(p0); d0 = ((unsigned)(hw0 >> 32) == he); }
                    if (!d1) { hw1 = agload64(p1); d1 = ((unsigned)(hw1 >> 32) == he); }
                }
            }
            hD[tid]       = __uint_as_float((unsigned)hw0);
            hD[tid + 512] = __uint_as_float((unsigned)hw1);
        }

        // ---- finalize inputs ----
        if constexpr (L == 0) {
            if (tid < 32) ((float4*)(s_x0 + par * 128))[tid] = sv;
        } else {
            if (tid < 64) {
                const unsigned xe = (unsigned)(t + 1);
                while ((unsigned)(gw >> 32) != xe) gw = agload64(gp);
                s_gi[par][tid] = __uint_as_float((unsigned)gw);
            }
        }
        __syncthreads();   // the ONE barrier per step

        // gi consumption progress: r0's barrier + h-coupling bounds all WGs
        if constexpr (L > 0) {
            if (r == 0 && tid == 0) agstorei(progGiSelf, t + 1);
        }

        // ---- hh dots: 4 units x 2 rows x 4 chunks = 32 dot4/thread ----
        float aF[4]  = {};
        float aNh[4] = {};
        float aNi[4] = {};
#pragma unroll
        for (int m = 0; m < 4; ++m) {
            const float4 h4 = ((const float4*)hD)[q + 64 * m];
#pragma unroll
            for (int g = 0; g < 4; ++g) {
                aF[g]  += dot4(wf[g][m], h4);
                aNh[g] += dot4(wn[g][m], h4);
            }
        }
        if constexpr (L == 0) {
            const float* xD = s_x0 + par * 128;
            const float2 x2 = *(const float2*)&xD[2 * q];
#pragma unroll
            for (int g = 0; g < 4; ++g) {
                aF[g]  += wif2[g].x * x2.x + wif2[g].y * x2.y;
                aNi[g] += win2[g].x * x2.x + win2[g].y * x2.y;
            }
        }

        // ---- three-phase reduction (4 units/wave) ----
#pragma unroll
        for (int g = 0; g < 4; ++g) {
            aF[g]  += __shfl_xor(aF[g],  1, 64);
            aNh[g] += __shfl_xor(aNh[g], 1, 64);
            if constexpr (L == 0) aNi[g] += __shfl_xor(aNi[g], 1, 64);
        }
        const int s1 = q & 1;
        float fF0  = s1 ? aF[1]  : aF[0];
        float fF1  = s1 ? aF[3]  : aF[2];
        float fNh0 = s1 ? aNh[1] : aNh[0];
        float fNh1 = s1 ? aNh[3] : aNh[2];
        float fNi0 = 0.f, fNi1 = 0.f;
        if constexpr (L == 0) {
            fNi0 = s1 ? aNi[1] : aNi[0];
            fNi1 = s1 ? aNi[3] : aNi[2];
        }
        fF0  += __shfl_xor(fF0,  2, 64);
        fF1  += __shfl_xor(fF1,  2, 64);
        fNh0 += __shfl_xor(fNh0, 2, 64);
        fNh1 += __shfl_xor(fNh1, 2, 64);
        if constexpr (L == 0) {
            fNi0 += __shfl_xor(fNi0, 2, 64);
            fNi1 += __shfl_xor(fNi1, 2, 64);
        }
        const int s2 = (q >> 1) & 1;
        float vF  = s2 ? fF1  : fF0;
        float vNh = s2 ? fNh1 : fNh0;
        float vNi = 0.f;
        if constexpr (L == 0) vNi = s2 ? fNi1 : fNi0;
#pragma unroll
        for (int off = 4; off <= 32; off <<= 1) {
            vF  += __shfl_xor(vF,  off, 64);
            vNh += __shfl_xor(vNh, off, 64);
            if constexpr (L == 0) vNi += __shfl_xor(vNi, off, 64);
        }

        // ---- gate + publish: lane q<4 -> unit jb+q ----
        if (q < 4) {
            const int   j  = jb + q;       // q == (q&1) + 2*((q>>1)&1)
            const float hp = hD[j];
            const float cF  = s1 ? (s2 ? bFv[3]  : bFv[1])  : (s2 ? bFv[2]  : bFv[0]);
            const float cHn = s1 ? (s2 ? bHnv[3] : bHnv[1]) : (s2 ? bHnv[2] : bHnv[0]);
            float f, n;
            if constexpr (L == 0) {
                const float cIn = s1 ? (s2 ? bInv[3] : bInv[1]) : (s2 ? bInv[2] : bInv[0]);
                f = 1.f / (1.f + expf(-(vF + cF)));
                n = tanhf(vNi + cIn + f * (vNh + cHn));
            } else {
                const float gf = s_gi[par][4 * a + q];        // w_ih f + b_ih
                const float gn = s_gi[par][32 + 4 * a + q];   // w_ih n + b_ih
                f = 1.f / (1.f + expf(-(gf + vF + cF)));
                n = tanhf(gn + f * (vNh + cHn));
            }
            const float hy = n + (1.f - f) * (hp - n);
            const u64   pk = pack(hy, t + 1);
            pub_dual(hpub + j, pk);        // sc0 home-L2 + sc1 MALL
            if constexpr (L < 2) {
                agstore64(ring_out + (size_t)(t & (RING - 1)) * HDIM + j, pk);
            } else {
                xout[(size_t)t * HDIM + j] = hy;
            }
        }
        // parity LDS buffers + per-step barrier bound intra-WG skew to 1.
    }
}

// ================= army (input-projection GEMV) =================
// 32 WGs x 512 threads per layer (XCDs 3/4; placement non-critical — pure
// MALL ring fabric). WG r owns units [32r, 32r+32); wave a owns 4 units.
__device__ void army_layer(float* __restrict__ s_x,        // LDS [2][1024]
                           const u64* __restrict__ xring,
                           u64* __restrict__ giRing,
                           const float* __restrict__ w_ih,
                           const float* __restrict__ b_ih,
                           const int* __restrict__ progGiNext, // 1 word
                           int* __restrict__ progSelf,         // own word
                           int r)
{
    const int tid = threadIdx.x;
    const int a   = tid >> 6;
    const int q   = tid & 63;
    const int jb  = r * 32 + 4 * a;

    float4 wiF[4][4], wiN[4][4];
#pragma unroll
    for (int g = 0; g < 4; ++g) {
        const float* rf = w_ih + (size_t)(jb + g) * HDIM;
        const float* rn = w_ih + (size_t)(HDIM + jb + g) * HDIM;
#pragma unroll
        for (int m = 0; m < 4; ++m) {
            wiF[g][m] = *(const float4*)(rf + 4 * q + 256 * m);
            wiN[g][m] = *(const float4*)(rn + 4 * q + 256 * m);
            opaque4(wiF[g][m]); opaque4(wiN[g][m]);
        }
    }
    float bIF[4], bIN[4];
#pragma unroll
    for (int g = 0; g < 4; ++g) {
        bIF[g] = b_ih[jb + g];
        bIN[g] = b_ih[HDIM + jb + g];
    }

    int lastProg = 0;

    for (int t = 0; t < T_STEPS; ++t) {
        const int par = t & 1;
        float* xD = s_x + par * HDIM;

        // gi-ring backpressure on the consumer layer's progress
        if (t - lastProg > SLACK) {
            do { lastProg = agloadi(progGiNext); } while (t - lastProg > SLACK);
        }

        // x acquire: 2 tagged words/thread (distributed agent-scope poll)
        {
            const unsigned xe = (unsigned)(t + 1);
            const u64* xrow = xring + (size_t)(t & (RING - 1)) * HDIM;
            u64 w0 = 0, w1 = 0;
            bool d0 = false, d1 = false;
            while (!(d0 && d1)) {
                if (!d0) { w0 = agload64(xrow + tid);       d0 = ((unsigned)(w0 >> 32) == xe); }
                if (!d1) { w1 = agload64(xrow + tid + 512); d1 = ((unsigned)(w1 >> 32) == xe); }
            }
            xD[tid]       = __uint_as_float((unsigned)w0);
            xD[tid + 512] = __uint_as_float((unsigned)w1);
        }
        __syncthreads();

        // per-WG consumption progress (army WGs are not step-coupled)
        if (tid == 0) agstorei(progSelf, t + 1);

        // dots: 4 units x 2 rows x 4 chunks = 32 dot4/thread
        float aGF[4] = {};
        float aGN[4] = {};
#pragma unroll
        for (int m = 0; m < 4; ++m) {
            const float4 x4 = ((const float4*)xD)[q + 64 * m];
#pragma unroll
            for (int g = 0; g < 4; ++g) {
                aGF[g] += dot4(wiF[g][m], x4);
                aGN[g] += dot4(wiN[g][m], x4);
            }
        }

        // three-phase reduction for 4 units
#pragma unroll
        for (int g = 0; g < 4; ++g) {
            aGF[g] += __shfl_xor(aGF[g], 1, 64);
            aGN[g] += __shfl_xor(aGN[g], 1, 64);
        }
        const int s1 = q & 1;
        float bF0 = s1 ? aGF[1] : aGF[0];
        float bF1 = s1 ? aGF[3] : aGF[2];
        float bN0 = s1 ? aGN[1] : aGN[0];
        float bN1 = s1 ? aGN[3] : aGN[2];
        bF0 += __shfl_xor(bF0, 2, 64);
        bF1 += __shfl_xor(bF1, 2, 64);
        bN0 += __shfl_xor(bN0, 2, 64);
        bN1 += __shfl_xor(bN1, 2, 64);
        const int s2 = (q >> 1) & 1;
        float vGF = s2 ? bF1 : bF0;
        float vGN = s2 ? bN1 : bN0;
#pragma unroll
        for (int off = 4; off <= 32; off <<= 1) {
            vGF += __shfl_xor(vGF, off, 64);
            vGN += __shfl_xor(vGN, off, 64);
        }

        // publish: lane q<4 -> unit jb+q (static-index bias select)
        if (q < 4) {
            const int j = jb + q;
            u64* grow = giRing + (size_t)(t & (RING - 1)) * 2048;
            const float bf = s1 ? (s2 ? bIF[3] : bIF[1]) : (s2 ? bIF[2] : bIF[0]);
            const float bn = s1 ? (s2 ? bIN[3] : bIN[1]) : (s2 ? bIN[2] : bIN[0]);
            agstore64(grow + j,        pack(vGF + bf, t + 1));
            agstore64(grow + 1024 + j, pack(vGN + bn, t + 1));
        }
    }
}

// ================= kernels =================
__global__ __launch_bounds__(512, 2)   // 256-reg cap, 1 block/CU (R6 regime)
void mgu_pipe(const float* __restrict__ S,
              const float* __restrict__ h0,
              const float* __restrict__ w_ih0, const float* __restrict__ b_ih0,
              const float* __restrict__ w_hh0, const float* __restrict__ b_hh0,
              const float* __restrict__ w_ih_r, const float* __restrict__ b_ih_r,
              const float* __restrict__ w_hh_r, const float* __restrict__ b_hh_r,
              float* __restrict__ xbuf2, u64* __restrict__ ring0,
              u64* __restrict__ ring1, u64* __restrict__ gi1,
              u64* __restrict__ gi2, u64* __restrict__ htag,
              int* __restrict__ prog)
{
    __shared__ __align__(16) float s_h[2 * HDIM];   // rec: h / army: x
    __shared__ __align__(16) float s_x0[2 * 128];   // L0 S-row staging
    __shared__ float s_gi[2][64];                   // rec L>0 gi staging

    int* prog_gi1 = prog + 0;     // L1 gi consumption (single word)
    int* prog_gi2 = prog + 16;    // L2 gi consumption (single word)
    int* prog_a1  = prog + 64;    // army1 per-WG x consumption [32]
    int* prog_a2  = prog + 128;   // army2 per-WG x consumption [32]

    const int role = blockIdx.x & 7;   // == XCD under round-robin dispatch
    const int r    = blockIdx.x >> 3;  // rank within role
    if (r >= 32) return;               // 352 filler blocks exit

    if (role == 0) {
        rec_layer<0>(s_h, s_x0, s_gi, S, h0,
                     w_ih0, b_ih0, w_hh0, b_hh0,
                     nullptr, ring0, nullptr,
                     htag, prog_a1, nullptr, r);
    } else if (role == 1) {
        rec_layer<1>(s_h, nullptr, s_gi, nullptr, h0 + HDIM,
                     nullptr, nullptr, w_hh_r, b_hh_r,
                     gi1, ring1, nullptr,
                     htag + 2 * HDIM, prog_a2, prog_gi1, r);
    } else if (role == 2) {
        rec_layer<2>(s_h, nullptr, s_gi, nullptr, h0 + 2 * HDIM,
                     nullptr, nullptr, w_hh_r + 2048 * 1024, b_hh_r + 2048,
                     gi2, nullptr, xbuf2,
                     htag + 4 * HDIM, nullptr, prog_gi2, r);
    } else if (role == 3) {
        army_layer(s_h, ring0, gi1, w_ih_r, b_ih_r,
                   prog_gi1, prog_a1 + r, r);
    } else if (role == 4) {
        army_layer(s_h, ring1, gi2, w_ih_r + 2048 * 1024, b_ih_r + 2048,
                   prog_gi2, prog_a2 + r, r);
    }
    // roles 5..7: exit
}

__global__ __launch_bounds__(256)
void mgu_out(const float* __restrict__ x,       // [T, H]
             const float* __restrict__ w_out,   // [1, H]
             const float* __restrict__ b_out,   // [1]
             float* __restrict__ out)           // [T]
{
    const int wave = threadIdx.x >> 6;
    const int lane = threadIdx.x & 63;
    const int t = blockIdx.x * 4 + wave;
    float acc = 0.f;
#pragma unroll
    for (int m = 0; m < 4; ++m) {
        const int i4 = lane + 64 * m;
        const float4 x4 = ((const float4*)(x + (size_t)t * HDIM))[i4];
        const float4 w4 = ((const float4*)w_out)[i4];
        acc += dot4(x4, w4);
    }
#pragma unroll
    for (int off = 32; off > 0; off >>= 1) acc += __shfl_xor(acc, off, 64);
    if (lane == 0) out[t] = acc + b_out[0];
}

extern "C" void kernel_launch(void* const* d_in, const int* in_sizes, int n_in,
                              void* d_out, int out_size, void* d_ws, size_t ws_size,
                              hipStream_t stream) {
    const float* S      = (const float*)d_in[0];   // [8192,128]
    const float* h0     = (const float*)d_in[1];   // [3,1024]
    const float* w_ih0  = (const float*)d_in[2];   // [2048,128]
    const float* w_hh0  = (const float*)d_in[3];   // [2048,1024]
    const float* b_ih0  = (const float*)d_in[4];   // [2048]
    const float* b_hh0  = (const float*)d_in[5];   // [2048]
    const float* w_ih_r = (const float*)d_in[6];   // [2,2048,1024]
    const float* w_hh_r = (const float*)d_in[7];   // [2,2048,1024]
    const float* b_ih_r = (const float*)d_in[8];   // [2,2048]
    const float* b_hh_r = (const float*)d_in[9];   // [2,2048]
    const float* w_out  = (const float*)d_in[10];  // [1,1024]
    const float* b_out  = (const float*)d_in[11];  // [1]
    float* out = (float*)d_out;                    // [8192]

    char* ws = (char*)d_ws;
    float* xbuf2 = (float*)(ws);                        // 32 MB [T,H] f32
    u64*   ring0 = (u64*)(ws + (32u << 20));            // 1 MB  [RING,H] u64
    u64*   ring1 = (u64*)(ws + (33u << 20));            // 1 MB
    u64*   gi1   = (u64*)(ws + (34u << 20));            // 2 MB  [RING,2H] u64
    u64*   gi2   = (u64*)(ws + (36u << 20));            // 2 MB
    u64*   htag  = (u64*)(ws + (38u << 20));            // 3 x [2,H] u64
    int*   prog  = (int*)(ws + (38u << 20) + (64u << 10));  // 192 ints

    // No init kernel: tags use exact-match vs the 0xAA poison; progress
    // words use signed compares (0xAAAAAAAA is negative).
    mgu_pipe<<<512, 512, 0, stream>>>(S, h0, w_ih0, b_ih0, w_hh0, b_hh0,
                                      w_ih_r, b_ih_r, w_hh_r, b_hh_r,
                                      xbuf2, ring0, ring1, gi1, gi2,
                                      htag, prog);
    mgu_out<<<2048, 256, 0, stream>>>(xbuf2, w_out, b_out, out);
}

// Round 5
// 26053.745 us; speedup vs baseline: 3.8789x; 1.4779x over previous
//
#include <hip/hip_runtime.h>
#include <math.h>
#include <stdint.h>

// MGU RNN, T=8192, IN=128, H=1024, L=3 — R11: R6 fabric + paired 16B polls.
//
// Anchor: R6 (23.2 ms), the best verified kernel. Evidence: R8 (half the
// rec VALU work) == R6 -> not VALU-bound. R9 (concentrated epoch lines) 4x
// worse -> line concurrency is scarce; polling must stay DISTRIBUTED.
// R10 (XCD-local sc0) 1.7x worse -> locality scheme dead as implemented.
// Remaining untested theory: the poll fabric SATURATES MALL request
// throughput (~98K threads x 4 independent 8B agent loads per ~900cy round)
// and inflates its own round-trip.
//
// R11 is R6 with exactly ONE variable changed: each thread owns two
// ADJACENT tagged words (2*tid, 2*tid+1) and polls them with a single
// 16B global_load_dwordx4 (sc0 sc1 = MALL-coherent, same as agent atomics);
// producers publish their two adjacent units with a single 16B store.
// Requests/round halve; tags are still checked per 8B word (partial or
// stale halves simply retry -> R6's safety argument is unchanged; sub-8B
// tearing cannot occur at >=8B cache write granularity). A bounded
// per-step fallback (32 paired rounds -> proven __hip_atomic_load path)
// guards the flag-semantics assumption: worst case ~= R6, never a hang.
//
// Everything else (grid 192x512, launch_bounds(512,2), weights-in-VGPR,
// parity-2 h rows, 128-row x rings, amortized backpressure, one barrier
// per step, no init vs 0xAA poison) is byte-identical to R6.

#define T_STEPS 8192
#define HDIM 1024
#define RING 128
#define FBR 32          // paired-poll rounds before classic fallback

typedef unsigned long long u64;
typedef unsigned int u32x4v __attribute__((ext_vector_type(4)));

__device__ __forceinline__ u64 agload64(const u64* p) {
    return __hip_atomic_load(p, __ATOMIC_RELAXED, __HIP_MEMORY_SCOPE_AGENT);
}
__device__ __forceinline__ void agstore64(u64* p, u64 v) {
    __hip_atomic_store(p, v, __ATOMIC_RELAXED, __HIP_MEMORY_SCOPE_AGENT);
}
__device__ __forceinline__ int agloadi(const int* p) {
    return __hip_atomic_load(p, __ATOMIC_RELAXED, __HIP_MEMORY_SCOPE_AGENT);
}
__device__ __forceinline__ void agstorei(int* p, int v) {
    __hip_atomic_store(p, v, __ATOMIC_RELAXED, __HIP_MEMORY_SCOPE_AGENT);
}
__device__ __forceinline__ float dot4(float4 a, float4 b) {
    return a.x * b.x + a.y * b.y + a.z * b.z + a.w * b.w;
}
__device__ __forceinline__ u64 pack(float v, int tag) {
    return ((u64)(unsigned)tag << 32) | (u64)__float_as_uint(v);
}
__device__ __forceinline__ void opaque4(float4& v) {
    asm volatile("" : "+v"(v.x), "+v"(v.y), "+v"(v.z), "+v"(v.w));
}
__device__ __forceinline__ void opaque2(float2& v) {
    asm volatile("" : "+v"(v.x), "+v"(v.y));
}

// Issue one 16B load of two adjacent tagged words. Result must only be
// read after wait_vm0() (rule: sched_barrier after inline-asm waitcnt).
#define ISSUE_PAIR(dst, p)                                                  \
    asm volatile("global_load_dwordx4 %0, %1, off sc0 sc1"                  \
                 : "=&v"(dst) : "v"(p) : "memory")
__device__ __forceinline__ void wait_vm0() {
    asm volatile("s_waitcnt vmcnt(0)" ::: "memory");
    __builtin_amdgcn_sched_barrier(0);
}
// One 16B store of two adjacent tagged words (MALL-coherent).
__device__ __forceinline__ void agstore_pair(u64* p, u64 w0, u64 w1) {
    u32x4v v;
    v.x = (unsigned)w0; v.y = (unsigned)(w0 >> 32);
    v.z = (unsigned)w1; v.w = (unsigned)(w1 >> 32);
    asm volatile("global_store_dwordx4 %0, %1, off sc0 sc1"
                 :: "v"(p), "v"(v) : "memory");
}

// K: input width. L: layer index 0..2.
template <int K, int L>
__device__ void scan_layer(float* __restrict__ s_h,   // LDS [2][HDIM]
                           float* __restrict__ s_x,   // LDS [2][HDIM]
                           const float* __restrict__ S,         // L==0
                           const u64*  __restrict__ xring_in,   // L>0
                           u64*        __restrict__ xring_out,  // L<2
                           float*      __restrict__ xout,       // L==2
                           const float* __restrict__ h0,
                           const float* __restrict__ w_ih,
                           const float* __restrict__ b_ih,
                           const float* __restrict__ w_hh,
                           const float* __restrict__ b_hh,
                           u64* __restrict__ htag,              // [2,H]
                           int* __restrict__ progNext,          // L<2
                           int* __restrict__ progSelf,          // L>0
                           int r)
{
    const int tid = threadIdx.x;       // 0..511
    const int a   = tid >> 6;          // wave 0..7
    const int q   = tid & 63;          // lane
    const int jb  = r * 16 + 2 * a;    // wave owns units jb, jb+1

    // ---- weights -> VGPRs (128 floats/thread), pinned opaque ----
    float4 wf[2][4], wn[2][4];
#pragma unroll
    for (int g = 0; g < 2; ++g) {
        const float* rf = w_hh + (size_t)(jb + g) * HDIM;
        const float* rn = w_hh + (size_t)(HDIM + jb + g) * HDIM;
#pragma unroll
        for (int m = 0; m < 4; ++m) {
            wf[g][m] = *(const float4*)(rf + 4 * q + 256 * m);
            wn[g][m] = *(const float4*)(rn + 4 * q + 256 * m);
            opaque4(wf[g][m]); opaque4(wn[g][m]);
        }
    }
    float4 wif[2][4], win[2][4];   // K==1024
    float2 wif2[2], win2[2];       // K==128
    if constexpr (K == 1024) {
#pragma unroll
        for (int g = 0; g < 2; ++g) {
            const float* rf = w_ih + (size_t)(jb + g) * K;
            const float* rn = w_ih + (size_t)(HDIM + jb + g) * K;
#pragma unroll
            for (int m = 0; m < 4; ++m) {
                wif[g][m] = *(const float4*)(rf + 4 * q + 256 * m);
                win[g][m] = *(const float4*)(rn + 4 * q + 256 * m);
                opaque4(wif[g][m]); opaque4(win[g][m]);
            }
        }
    } else {
#pragma unroll
        for (int g = 0; g < 2; ++g) {
            wif2[g] = *(const float2*)(w_ih + (size_t)(jb + g) * K + 2 * q);
            win2[g] = *(const float2*)(w_ih + (size_t)(HDIM + jb + g) * K + 2 * q);
            opaque2(wif2[g]); opaque2(win2[g]);
        }
    }
    float bFv[2], bInv[2], bHnv[2];
#pragma unroll
    for (int g = 0; g < 2; ++g) {
        bFv[g]  = b_ih[jb + g] + b_hh[jb + g];
        bInv[g] = b_ih[HDIM + jb + g];
        bHnv[g] = b_hh[HDIM + jb + g];
    }

    int lastProg = 0;
    for (int t = 0; t < T_STEPS; ++t) {
        const int par = t & 1;
        const u64* hrow = htag + (size_t)((t + 1) & 1) * HDIM;  // parity of t-1
        u64*       hpub = htag + (size_t)par * HDIM;
        float* hD = s_h + par * HDIM;
        float* xD = s_x + par * HDIM;

        // ---- amortized ring backpressure (off critical path) ----
        if constexpr (L < 2) {
            if (t - lastProg > RING - 16) {
                do { lastProg = agloadi(progNext); } while (t - lastProg > RING - 16);
            }
        }

        // ---- paired poll: h words 2tid,2tid+1 ; x words 2tid,2tid+1 ----
        if (t == 0) {
            ((float2*)hD)[tid] = ((const float2*)h0)[tid];
        }
        {
            const unsigned he = (unsigned)t;
            const unsigned xe = (unsigned)(t + 1);
            const u64* hp2 = hrow + 2 * tid;
            const u64* xp2 = nullptr;
            if constexpr (L > 0)
                xp2 = xring_in + (size_t)(t & (RING - 1)) * HDIM + 2 * tid;
            bool hok = (t == 0);
            bool xok = (L == 0);
            u32x4v hv, xv;
            int rounds = 0;
            while (!(hok && xok)) {
                if (!hok) ISSUE_PAIR(hv, hp2);
                if constexpr (L > 0) { if (!xok) ISSUE_PAIR(xv, xp2); }
                wait_vm0();
                if (!hok) hok = (hv.y == he) && (hv.w == he);
                if constexpr (L > 0) {
                    if (!xok) xok = (xv.y == xe) && (xv.w == xe);
                }
                if (!(hok && xok) && ++rounds > FBR) {
                    // classic per-word fallback (proven agent-scope path);
                    // also absorbs genuine long waits (pipeline fill,
                    // backpressure stalls) without round bounds.
                    u64 hw0 = 0, hw1 = 0, xw0 = 0, xw1 = 0;
                    bool d0 = hok, d1 = hok, e0 = xok, e1 = xok;
                    while (!(d0 && d1 && e0 && e1)) {
                        if (!d0) { hw0 = agload64(hp2);     d0 = ((unsigned)(hw0 >> 32) == he); }
                        if (!d1) { hw1 = agload64(hp2 + 1); d1 = ((unsigned)(hw1 >> 32) == he); }
                        if constexpr (L > 0) {
                            if (!e0) { xw0 = agload64(xp2);     e0 = ((unsigned)(xw0 >> 32) == xe); }
                            if (!e1) { xw1 = agload64(xp2 + 1); e1 = ((unsigned)(xw1 >> 32) == xe); }
                        }
                    }
                    if (!hok) { hv.x = (unsigned)hw0; hv.z = (unsigned)hw1; hok = true; }
                    if constexpr (L > 0) {
                        if (!xok) { xv.x = (unsigned)xw0; xv.z = (unsigned)xw1; xok = true; }
                    }
                }
            }
            if (t > 0)
                ((float2*)hD)[tid] = make_float2(__uint_as_float(hv.x),
                                                 __uint_as_float(hv.z));
            if constexpr (L > 0)
                ((float2*)xD)[tid] = make_float2(__uint_as_float(xv.x),
                                                 __uint_as_float(xv.z));
        }
        if constexpr (L == 0) {
            if (tid < K / 4)
                ((float4*)xD)[tid] = ((const float4*)(S + (size_t)t * K))[tid];
        }
        __syncthreads();   // the ONE barrier per step

        // consumer progress: barrier proved ALL waves read x_t from global
        if constexpr (L > 0) {
            if (r == 0 && tid == 0) agstorei(progSelf, t + 1);
        }

        // ---- dots for units jb, jb+1 (conflict-free b128 LDS reads) ----
        float aF[2]  = {0.f, 0.f};
        float aNh[2] = {0.f, 0.f};
        float aNi[2] = {0.f, 0.f};
#pragma unroll
        for (int m = 0; m < 4; ++m) {
            const float4 h4 = ((const float4*)hD)[q + 64 * m];
#pragma unroll
            for (int g = 0; g < 2; ++g) {
                aF[g]  += dot4(wf[g][m], h4);
                aNh[g] += dot4(wn[g][m], h4);
            }
        }
        if constexpr (K == 1024) {
#pragma unroll
            for (int m = 0; m < 4; ++m) {
                const float4 x4 = ((const float4*)xD)[q + 64 * m];
#pragma unroll
                for (int g = 0; g < 2; ++g) {
                    aF[g]  += dot4(wif[g][m], x4);
                    aNi[g] += dot4(win[g][m], x4);
                }
            }
        } else {
            const float2 x2 = *(const float2*)&xD[2 * q];
#pragma unroll
            for (int g = 0; g < 2; ++g) {
                aF[g]  += wif2[g].x * x2.x + wif2[g].y * x2.y;
                aNi[g] += win2[g].x * x2.x + win2[g].y * x2.y;
            }
        }

        // ---- two-phase reduction: pair butterfly, select, stride butterfly
#pragma unroll
        for (int g = 0; g < 2; ++g) {
            aF[g]  += __shfl_xor(aF[g],  1, 64);
            aNh[g] += __shfl_xor(aNh[g], 1, 64);
            aNi[g] += __shfl_xor(aNi[g], 1, 64);
        }
        const int gs = q & 1;
        float vF  = gs ? aF[1]  : aF[0];
        float vNh = gs ? aNh[1] : aNh[0];
        float vNi = gs ? aNi[1] : aNi[0];
#pragma unroll
        for (int off = 2; off <= 32; off <<= 1) {
            vF  += __shfl_xor(vF,  off, 64);
            vNh += __shfl_xor(vNh, off, 64);
            vNi += __shfl_xor(vNi, off, 64);
        }

        // ---- gate on ALL lanes (wave-wide VALU cost == 2-lane cost);
        //      gs selects unit jb / jb+1; lane 0 publishes the 16B pair ----
        {
            const float cF  = gs ? bFv[1]  : bFv[0];
            const float cIn = gs ? bInv[1] : bInv[0];
            const float cHn = gs ? bHnv[1] : bHnv[0];
            const float hp  = hD[jb + gs];
            const float f   = 1.f / (1.f + expf(-(vF + cF)));
            const float n   = tanhf(vNi + cIn + f * (vNh + cHn));
            const float hy  = n + (1.f - f) * (hp - n);
            const u64   pk  = pack(hy, t + 1);
            const u64   pk1 = __shfl(pk, 1, 64);    // lane 1's word
            if (q == 0) {
                agstore_pair(hpub + jb, pk, pk1);
                if constexpr (L < 2) {
                    agstore_pair(xring_out + (size_t)(t & (RING - 1)) * HDIM + jb,
                                 pk, pk1);
                } else {
                    ((float2*)(xout + (size_t)t * HDIM))[jb >> 1] =
                        make_float2(hy, __uint_as_float((unsigned)pk1));
                }
            }
        }
        // no trailing barrier: parity LDS buffers + per-step barrier bound
        // intra-WG skew to 1 step.
    }
}

__global__ __launch_bounds__(512, 2)
void mgu_pipe(const float* __restrict__ S,
              const float* __restrict__ h0,
              const float* __restrict__ w_ih0, const float* __restrict__ b_ih0,
              const float* __restrict__ w_hh0, const float* __restrict__ b_hh0,
              const float* __restrict__ w_ih_r, const float* __restrict__ b_ih_r,
              const float* __restrict__ w_hh_r, const float* __restrict__ b_hh_r,
              float* __restrict__ xbuf2, u64* __restrict__ ring0,
              u64* __restrict__ ring1, u64* __restrict__ htag,
              int* __restrict__ prog)
{
    __shared__ __align__(16) float s_h[2 * HDIM];
    __shared__ __align__(16) float s_x[2 * HDIM];
    const int grp = blockIdx.x >> 6;
    const int r   = blockIdx.x & 63;
    if (grp == 0) {
        scan_layer<128, 0>(s_h, s_x, S, nullptr, ring0, nullptr, h0,
                           w_ih0, b_ih0, w_hh0, b_hh0,
                           htag, prog + 1, nullptr, r);
    } else if (grp == 1) {
        scan_layer<1024, 1>(s_h, s_x, nullptr, ring0, ring1, nullptr, h0 + HDIM,
                            w_ih_r, b_ih_r, w_hh_r, b_hh_r,
                            htag + 2 * HDIM, prog + 2, prog + 1, r);
    } else {
        scan_layer<1024, 2>(s_h, s_x, nullptr, ring1, nullptr, xbuf2,
                            h0 + 2 * HDIM,
                            w_ih_r + 2048 * 1024, b_ih_r + 2048,
                            w_hh_r + 2048 * 1024, b_hh_r + 2048,
                            htag + 4 * HDIM, nullptr, prog + 2, r);
    }
}

__global__ __launch_bounds__(256)
void mgu_out(const float* __restrict__ x,       // [T, H]
             const float* __restrict__ w_out,   // [1, H]
             const float* __restrict__ b_out,   // [1]
             float* __restrict__ out)           // [T]
{
    const int wave = threadIdx.x >> 6;
    const int lane = threadIdx.x & 63;
    const int t = blockIdx.x * 4 + wave;
    float acc = 0.f;
#pragma unroll
    for (int m = 0; m < 4; ++m) {
        const int i4 = lane + 64 * m;
        const float4 x4 = ((const float4*)(x + (size_t)t * HDIM))[i4];
        const float4 w4 = ((const float4*)w_out)[i4];
        acc += dot4(x4, w4);
    }
#pragma unroll
    for (int off = 32; off > 0; off >>= 1) acc += __shfl_xor(acc, off, 64);
    if (lane == 0) out[t] = acc + b_out[0];
}

extern "C" void kernel_launch(void* const* d_in, const int* in_sizes, int n_in,
                              void* d_out, int out_size, void* d_ws, size_t ws_size,
                              hipStream_t stream) {
    const float* S      = (const float*)d_in[0];   // [8192,128]
    const float* h0     = (const float*)d_in[1];   // [3,1024]
    const float* w_ih0  = (const float*)d_in[2];   // [2048,128]
    const float* w_hh0  = (const float*)d_in[3];   // [2048,1024]
    const float* b_ih0  = (const float*)d_in[4];   // [2048]
    const float* b_hh0  = (const float*)d_in[5];   // [2048]
    const float* w_ih_r = (const float*)d_in[6];   // [2,2048,1024]
    const float* w_hh_r = (const float*)d_in[7];   // [2,2048,1024]
    const float* b_ih_r = (const float*)d_in[8];   // [2,2048]
    const float* b_hh_r = (const float*)d_in[9];   // [2,2048]
    const float* w_out  = (const float*)d_in[10];  // [1,1024]
    const float* b_out  = (const float*)d_in[11];  // [1]
    float* out = (float*)d_out;                    // [8192]

    char* ws = (char*)d_ws;
    float* xbuf2 = (float*)(ws);                        // 32 MB  [T,H] f32
    u64*   ring0 = (u64*)(ws + (32u << 20));            // 1 MB   [RING,H] u64
    u64*   ring1 = (u64*)(ws + (33u << 20));            // 1 MB
    u64*   htag  = (u64*)(ws + (34u << 20));            // 3 x [2,H] u64
    int*   prog  = (int*)(ws + (34u << 20) + (64u << 10));

    // No init kernel: tags/progress use exact-match vs the 0xAA poison.
    mgu_pipe<<<192, 512, 0, stream>>>(S, h0, w_ih0, b_ih0, w_hh0, b_hh0,
                                      w_ih_r, b_ih_r, w_hh_r, b_hh_r,
                                      xbuf2, ring0, ring1, htag, prog);
    mgu_out<<<2048, 256, 0, stream>>>(xbuf2, w_out, b_out, out);
}